// Round 1
// baseline (75791.949 us; speedup 1.0000x reference)
//
#include <hip/hip_runtime.h>
#include <math.h>

// Problem constants
#define Bx 64
#define Tx 800
#define Ux 80
#define INx 3
#define Hx 400
#define Vx 57
#define Kx 10

// Layouts (all activations [t][feat][b], b fastest => coalesced over lanes):
//  out0/out12 : t*25600 + h*64 + b      (Hx*Bx = 25600)
//  win        : t*3648  + v*64 + b      (Vx*Bx = 3648)
//  abk        : t*1920  + j*64 + b      (30*Bx = 1920)
//  xg chunk   : tt*76800 + g*64 + b     (1200*Bx = 76800), tt in [0,80)
//  xT         : t*192   + d*64 + b
//  ohT        : (u*57+v)*64 + b

__device__ __forceinline__ float sigf(float x) { return 1.f / (1.f + expf(-x)); }

__global__ void k_transpose_x(const float* __restrict__ x, float* __restrict__ xT) {
    int idx = blockIdx.x * blockDim.x + threadIdx.x;
    if (idx >= Tx * INx * Bx) return;
    int b = idx & 63;
    int d = (idx >> 6) % INx;
    int t = idx / (64 * INx);
    xT[idx] = x[((size_t)b * Tx + t) * INx + d];
}

__global__ void k_transpose_oh(const float* __restrict__ oh, float* __restrict__ ohT) {
    int idx = blockIdx.x * blockDim.x + threadIdx.x;
    if (idx >= Ux * Vx * Bx) return;
    int b = idx & 63;
    int uv = idx >> 6;
    int v = uv % Vx;
    int u = uv / Vx;
    ohT[idx] = oh[((size_t)b * Ux + u) * Vx + v];
}

// GRU layer 0 step: input projection (3-dim) inline. grid 100 blocks x 256 thr.
__global__ __launch_bounds__(256) void k_step0(
    const float* __restrict__ xT, const float* __restrict__ h0,
    const float* __restrict__ Wih, const float* __restrict__ Whh,
    const float* __restrict__ bih, const float* __restrict__ bhh,
    float* __restrict__ out0, int t) {
    int b = threadIdx.x & 63;
    int du = threadIdx.x >> 6;
    int u = blockIdx.x * 4 + du;

    const float* hb; int sk, sb;
    if (t == 0) { hb = h0; sk = 1; sb = Hx; }
    else { hb = out0 + (size_t)(t - 1) * 25600; sk = 64; sb = 1; }

    float x0 = xT[t * 192 + b];
    float x1 = xT[t * 192 + 64 + b];
    float x2 = xT[t * 192 + 128 + b];

    float ar = bih[u]          + Wih[u * 3] * x0          + Wih[u * 3 + 1] * x1          + Wih[u * 3 + 2] * x2;
    float az = bih[Hx + u]     + Wih[(Hx + u) * 3] * x0   + Wih[(Hx + u) * 3 + 1] * x1   + Wih[(Hx + u) * 3 + 2] * x2;
    float an = bih[2 * Hx + u] + Wih[(2 * Hx + u) * 3] * x0 + Wih[(2 * Hx + u) * 3 + 1] * x1 + Wih[(2 * Hx + u) * 3 + 2] * x2;

    float hr = bhh[u], hz = bhh[Hx + u], hn = bhh[2 * Hx + u];
    const float* wr = Whh + (size_t)u * Hx;
    const float* wz = Whh + (size_t)(Hx + u) * Hx;
    const float* wn = Whh + (size_t)(2 * Hx + u) * Hx;

    for (int k = 0; k < Hx; k += 4) {
        float4 a = *(const float4*)(wr + k);
        float4 c = *(const float4*)(wz + k);
        float4 d = *(const float4*)(wn + k);
        float h0v = hb[(k + 0) * sk + b * sb];
        float h1v = hb[(k + 1) * sk + b * sb];
        float h2v = hb[(k + 2) * sk + b * sb];
        float h3v = hb[(k + 3) * sk + b * sb];
        hr += a.x * h0v + a.y * h1v + a.z * h2v + a.w * h3v;
        hz += c.x * h0v + c.y * h1v + c.z * h2v + c.w * h3v;
        hn += d.x * h0v + d.y * h1v + d.z * h2v + d.w * h3v;
    }
    float r = sigf(ar + hr);
    float z = sigf(az + hz);
    float n = tanhf(an + r * hn);
    float hpu = hb[u * sk + b * sb];
    out0[(size_t)t * 25600 + u * 64 + b] = (1.f - z) * n + z * hpu;
}

// abk = exp(out0 @ W_win^T + b_win), parallel over t. grid 800 x 256.
__global__ __launch_bounds__(256) void k_abk(const float* __restrict__ out0,
    const float* __restrict__ Wwin, const float* __restrict__ bwin,
    float* __restrict__ abk) {
    int t = blockIdx.x;
    int b = threadIdx.x & 63;
    int js = threadIdx.x >> 6;
    int j0 = js * 8;
    int nj = min(8, 30 - j0);   // 8,8,8,6
    float acc[8];
    for (int i = 0; i < nj; i++) acc[i] = bwin[j0 + i];
    const float* o = out0 + (size_t)t * 25600;
    for (int k = 0; k < Hx; k++) {
        float hv = o[k * 64 + b];
        for (int i = 0; i < nj; i++) acc[i] += Wwin[(j0 + i) * Hx + k] * hv;
    }
    for (int i = 0; i < nj; i++)
        abk[(size_t)t * 1920 + (j0 + i) * 64 + b] = expf(acc[i]);
}

// In-place cumsum of kappa slots (j=20..29) over t. 640 independent chains.
__global__ void k_cumsum(float* __restrict__ abk) {
    int tid = blockIdx.x * blockDim.x + threadIdx.x;
    if (tid >= Kx * Bx) return;
    int b = tid & 63;
    int k = tid >> 6;
    float run = 0.f;
    size_t base = (size_t)(20 + k) * 64 + b;
    for (int t = 0; t < Tx; t++) {
        size_t i = (size_t)t * 1920 + base;
        run += abk[i];
        abk[i] = run;
    }
}

// phi + window, parallel over t. grid 800 x 256.
__global__ __launch_bounds__(256) void k_window(const float* __restrict__ abk,
    const float* __restrict__ ohT, float* __restrict__ win) {
    int t = blockIdx.x;
    int b = threadIdx.x & 63;
    int sub = threadIdx.x >> 6;
    __shared__ float phi[Ux][64];

    float al[Kx], be[Kx], kc[Kx];
    const float* ab = abk + (size_t)t * 1920;
    #pragma unroll
    for (int k = 0; k < Kx; k++) {
        al[k] = ab[k * 64 + b];
        be[k] = ab[(10 + k) * 64 + b];
        kc[k] = ab[(20 + k) * 64 + b];
    }
    for (int u = sub * 20; u < sub * 20 + 20; u++) {
        float s = 0.f;
        float uf = (float)u;
        #pragma unroll
        for (int k = 0; k < Kx; k++) {
            float d = kc[k] - uf;
            s += al[k] * __expf(-be[k] * d * d);
        }
        phi[u][b] = s;
    }
    __syncthreads();

    int v0 = sub * 15;
    int nv = min(15, Vx - v0);  // 15,15,15,12
    float acc[15];
    for (int i = 0; i < nv; i++) acc[i] = 0.f;
    for (int u = 0; u < Ux; u++) {
        float pv = phi[u][b];
        const float* oh = ohT + (size_t)(u * Vx) * 64;
        for (int i = 0; i < nv; i++) acc[i] += pv * oh[(v0 + i) * 64 + b];
    }
    for (int i = 0; i < nv; i++)
        win[(size_t)t * 3648 + (v0 + i) * 64 + b] = acc[i];
}

// Input-side projection for layers 1/2, one T-chunk of 80 steps.
// grid (80, 75), block 256: 16 gate rows per block-y tile, 4 per thread.
__global__ __launch_bounds__(256) void k_xg(const float* __restrict__ outprev,
    const float* __restrict__ win, const float* __restrict__ xT,
    const float* __restrict__ Wih, const float* __restrict__ bih,
    float* __restrict__ xg, int c) {
    int tt = blockIdx.x;
    int gt = blockIdx.y;
    int t = c * 80 + tt;
    int b = threadIdx.x & 63;
    int du = threadIdx.x >> 6;
    int g = gt * 16 + du * 4;

    float a0 = bih[g], a1 = bih[g + 1], a2 = bih[g + 2], a3 = bih[g + 3];
    const float* w0 = Wih + (size_t)g * 460;
    const float* w1 = w0 + 460;
    const float* w2 = w0 + 920;
    const float* w3 = w0 + 1380;

    const float* op = outprev + (size_t)t * 25600;
    for (int d = 0; d < 400; d += 4) {
        float4 q0 = *(const float4*)(w0 + d);
        float4 q1 = *(const float4*)(w1 + d);
        float4 q2 = *(const float4*)(w2 + d);
        float4 q3 = *(const float4*)(w3 + d);
        float i0 = op[d * 64 + b];
        float i1 = op[(d + 1) * 64 + b];
        float i2 = op[(d + 2) * 64 + b];
        float i3 = op[(d + 3) * 64 + b];
        a0 += q0.x * i0 + q0.y * i1 + q0.z * i2 + q0.w * i3;
        a1 += q1.x * i0 + q1.y * i1 + q1.z * i2 + q1.w * i3;
        a2 += q2.x * i0 + q2.y * i1 + q2.z * i2 + q2.w * i3;
        a3 += q3.x * i0 + q3.y * i1 + q3.z * i2 + q3.w * i3;
    }
    const float* wp = win + (size_t)t * 3648;
    for (int d = 0; d < Vx; d++) {
        float iv = wp[d * 64 + b];
        a0 += w0[400 + d] * iv;
        a1 += w1[400 + d] * iv;
        a2 += w2[400 + d] * iv;
        a3 += w3[400 + d] * iv;
    }
    const float* xp = xT + (size_t)t * 192;
    #pragma unroll
    for (int d = 0; d < 3; d++) {
        float iv = xp[d * 64 + b];
        a0 += w0[457 + d] * iv;
        a1 += w1[457 + d] * iv;
        a2 += w2[457 + d] * iv;
        a3 += w3[457 + d] * iv;
    }
    size_t o = (size_t)tt * 76800 + (size_t)g * 64 + b;
    xg[o] = a0;
    xg[o + 64] = a1;
    xg[o + 128] = a2;
    xg[o + 192] = a3;
}

// GRU layer 1/2 step: x-side comes precomputed from xg chunk (incl. b_ih).
__global__ __launch_bounds__(256) void k_step12(
    const float* __restrict__ hinit, const float* __restrict__ xg,
    const float* __restrict__ Whh, const float* __restrict__ bhh,
    float* __restrict__ outL, int t, int tt) {
    int b = threadIdx.x & 63;
    int du = threadIdx.x >> 6;
    int u = blockIdx.x * 4 + du;

    const float* hb; int sk, sb;
    if (t == 0) { hb = hinit; sk = 1; sb = Hx; }
    else { hb = outL + (size_t)(t - 1) * 25600; sk = 64; sb = 1; }

    const float* xgp = xg + (size_t)tt * 76800;
    float ar = xgp[u * 64 + b];
    float az = xgp[(Hx + u) * 64 + b];
    float an = xgp[(2 * Hx + u) * 64 + b];

    float hr = bhh[u], hz = bhh[Hx + u], hn = bhh[2 * Hx + u];
    const float* wr = Whh + (size_t)u * Hx;
    const float* wz = Whh + (size_t)(Hx + u) * Hx;
    const float* wn = Whh + (size_t)(2 * Hx + u) * Hx;

    for (int k = 0; k < Hx; k += 4) {
        float4 a = *(const float4*)(wr + k);
        float4 c = *(const float4*)(wz + k);
        float4 d = *(const float4*)(wn + k);
        float h0v = hb[(k + 0) * sk + b * sb];
        float h1v = hb[(k + 1) * sk + b * sb];
        float h2v = hb[(k + 2) * sk + b * sb];
        float h3v = hb[(k + 3) * sk + b * sb];
        hr += a.x * h0v + a.y * h1v + a.z * h2v + a.w * h3v;
        hz += c.x * h0v + c.y * h1v + c.z * h2v + c.w * h3v;
        hn += d.x * h0v + d.y * h1v + d.z * h2v + d.w * h3v;
    }
    float r = sigf(ar + hr);
    float z = sigf(az + hz);
    float n = tanhf(an + r * hn);
    float hpu = hb[u * sk + b * sb];
    outL[(size_t)t * 25600 + u * 64 + b] = (1.f - z) * n + z * hpu;
}

// MDN head: out[(b*T+t)*121 + j], tanh on j in [100,120). grid 800 x 256.
__global__ __launch_bounds__(256) void k_mdn(const float* __restrict__ out2,
    const float* __restrict__ Wm, const float* __restrict__ bm,
    float* __restrict__ out) {
    int t = blockIdx.x;
    int b = threadIdx.x & 63;
    int js = threadIdx.x >> 6;
    int j0 = js * 31;
    int nj = min(31, 121 - j0);   // 31,31,31,28
    float acc[31];
    for (int i = 0; i < nj; i++) acc[i] = bm[j0 + i];
    const float* o = out2 + (size_t)t * 25600;
    for (int k = 0; k < Hx; k += 4) {
        float i0 = o[k * 64 + b];
        float i1 = o[(k + 1) * 64 + b];
        float i2 = o[(k + 2) * 64 + b];
        float i3 = o[(k + 3) * 64 + b];
        for (int i = 0; i < nj; i++) {
            const float* w = Wm + (size_t)(j0 + i) * Hx + k;
            float4 q = *(const float4*)w;
            acc[i] += q.x * i0 + q.y * i1 + q.z * i2 + q.w * i3;
        }
    }
    size_t rb = ((size_t)b * Tx + t) * 121;
    for (int i = 0; i < nj; i++) {
        int j = j0 + i;
        float v = acc[i];
        if (j >= 100 && j < 120) v = tanhf(v);
        out[rb + j] = v;
    }
}

extern "C" void kernel_launch(void* const* d_in, const int* in_sizes, int n_in,
                              void* d_out, int out_size, void* d_ws, size_t ws_size,
                              hipStream_t stream) {
    const float* x    = (const float*)d_in[0];
    const float* oneh = (const float*)d_in[1];
    const float* h0i  = (const float*)d_in[2];
    const float* h1i  = (const float*)d_in[3];
    const float* h2i  = (const float*)d_in[4];
    const float* Wih0 = (const float*)d_in[5];
    const float* Whh0 = (const float*)d_in[6];
    const float* bih0 = (const float*)d_in[7];
    const float* bhh0 = (const float*)d_in[8];
    const float* Wih1 = (const float*)d_in[9];
    const float* Whh1 = (const float*)d_in[10];
    const float* bih1 = (const float*)d_in[11];
    const float* bhh1 = (const float*)d_in[12];
    const float* Wwin = (const float*)d_in[13];
    const float* bwin = (const float*)d_in[14];
    const float* Wmdn = (const float*)d_in[15];
    const float* bmdn = (const float*)d_in[16];

    float* ws    = (float*)d_ws;
    float* out0  = ws;                  // 20,480,000 floats
    float* out12 = ws + 20480000;       // 20,480,000
    float* winb  = ws + 40960000;       //  2,918,400
    float* abk   = ws + 43878400;       //  1,536,000
    float* xg    = ws + 45414400;       //  6,144,000 (80-step chunk)
    float* xT    = ws + 51558400;       //    153,600
    float* ohT   = ws + 51712000;       //    291,840
    // total: 52,003,840 floats = 208.0 MB

    hipLaunchKernelGGL(k_transpose_x, dim3((Tx * INx * Bx + 255) / 256), dim3(256), 0, stream, x, xT);
    hipLaunchKernelGGL(k_transpose_oh, dim3((Ux * Vx * Bx + 255) / 256), dim3(256), 0, stream, oneh, ohT);

    for (int t = 0; t < Tx; t++)
        hipLaunchKernelGGL(k_step0, dim3(100), dim3(256), 0, stream,
                           xT, h0i, Wih0, Whh0, bih0, bhh0, out0, t);

    hipLaunchKernelGGL(k_abk, dim3(Tx), dim3(256), 0, stream, out0, Wwin, bwin, abk);
    hipLaunchKernelGGL(k_cumsum, dim3(10), dim3(64), 0, stream, abk);
    hipLaunchKernelGGL(k_window, dim3(Tx), dim3(256), 0, stream, abk, ohT, winb);

    // Layer 1 (input: out0, win, x), chunked xg
    for (int c = 0; c < 10; c++) {
        hipLaunchKernelGGL(k_xg, dim3(80, 75), dim3(256), 0, stream,
                           out0, winb, xT, Wih1, bih1, xg, c);
        for (int tt = 0; tt < 80; tt++) {
            int t = c * 80 + tt;
            hipLaunchKernelGGL(k_step12, dim3(100), dim3(256), 0, stream,
                               h1i, xg, Whh1, bhh1, out12, t, tt);
        }
    }
    // Layer 2 (input: out12, win, x), same weights; output reuses out0 buffer
    for (int c = 0; c < 10; c++) {
        hipLaunchKernelGGL(k_xg, dim3(80, 75), dim3(256), 0, stream,
                           out12, winb, xT, Wih1, bih1, xg, c);
        for (int tt = 0; tt < 80; tt++) {
            int t = c * 80 + tt;
            hipLaunchKernelGGL(k_step12, dim3(100), dim3(256), 0, stream,
                               h2i, xg, Whh1, bhh1, out0, t, tt);
        }
    }
    hipLaunchKernelGGL(k_mdn, dim3(Tx), dim3(256), 0, stream, out0, Wmdn, bmdn, (float*)d_out);
}

// Round 2
// 63596.735 us; speedup vs baseline: 1.1918x; 1.1918x over previous
//
#include <hip/hip_runtime.h>
#include <math.h>

// Problem constants
#define Bx 64
#define Tx 800
#define Ux 80
#define INx 3
#define Hx 400
#define Vx 57
#define Kx 10
#define KJ 200      // k-pairs (400/2)
#define TT 40       // steps per layer-1/2 chunk
#define NC 20       // chunks

// Layouts:
//  out0/out12 : t*25600 + h*64 + b          (b fastest)
//  win        : t*3648  + v*64 + b
//  abk        : t*1920  + j*64 + b
//  xg chunk   : tt*76800 + (b>>1)*2400 + g*2 + (b&1)   [tt][bpair][gate][2]
//  xT         : t*192   + d*64 + b
//  ohT        : (u*57+v)*64 + b
//  Wpk        : float2 index (j*400 + u)*3 + gate ; value = (Whh[g][2j], Whh[g][2j+1])

typedef float v2f __attribute__((ext_vector_type(2)));
typedef float v4f __attribute__((ext_vector_type(4)));

__device__ __forceinline__ float sigf(float x) { return 1.f / (1.f + expf(-x)); }

// acc.xy += w.x * h.xy   (broadcast LOW half of S0)
__device__ __forceinline__ void pk_lo(v2f& acc, v2f w, v2f h) {
    asm("v_pk_fma_f32 %0, %1, %2, %0 op_sel:[0,0,0] op_sel_hi:[0,1,1]"
        : "+v"(acc) : "v"(w), "v"(h));
}
// acc.xy += w.y * h.xy   (broadcast HIGH half of S0)
__device__ __forceinline__ void pk_hi(v2f& acc, v2f w, v2f h) {
    asm("v_pk_fma_f32 %0, %1, %2, %0 op_sel:[1,0,0] op_sel_hi:[1,1,1]"
        : "+v"(acc) : "v"(w), "v"(h));
}

__global__ void k_transpose_x(const float* __restrict__ x, float* __restrict__ xT) {
    int idx = blockIdx.x * blockDim.x + threadIdx.x;
    if (idx >= Tx * INx * Bx) return;
    int b = idx & 63;
    int d = (idx >> 6) % INx;
    int t = idx / (64 * INx);
    xT[idx] = x[((size_t)b * Tx + t) * INx + d];
}

__global__ void k_transpose_oh(const float* __restrict__ oh, float* __restrict__ ohT) {
    int idx = blockIdx.x * blockDim.x + threadIdx.x;
    if (idx >= Ux * Vx * Bx) return;
    int b = idx & 63;
    int uv = idx >> 6;
    int v = uv % Vx;
    int u = uv / Vx;
    ohT[idx] = oh[((size_t)b * Ux + u) * Vx + v];
}

// Pack Whh (3H x H row-major) -> [j][u][gate] float2 over k-pairs
__global__ void k_pack(const float* __restrict__ Whh, float* __restrict__ Wpk) {
    int idx = blockIdx.x * blockDim.x + threadIdx.x;   // 3*KJ*Hx = 240000 float2
    if (idx >= 3 * KJ * Hx) return;
    int gate = idx % 3;
    int u = (idx / 3) % Hx;
    int j = idx / (3 * Hx);
    const float* s = Whh + ((size_t)gate * Hx + u) * Hx + 2 * j;
    v2f val; val.x = s[0]; val.y = s[1];
    ((v2f*)Wpk)[idx] = val;
}

// Persistent layer-0 recurrence: 32 WGs (2 batch chains each) x 512 thr, 800 steps.
__global__ __launch_bounds__(512) void k_rec0(
    const float* __restrict__ xT, const float* __restrict__ hinit,
    const float* __restrict__ Wih, const float* __restrict__ Wpk,
    const float* __restrict__ bih, const float* __restrict__ bhh,
    float* __restrict__ outL) {
    __shared__ __align__(16) float hls[2][2 * Hx];
    const int u = threadIdx.x;
    const int bp = blockIdx.x, bb = bp * 2;
    const bool act = (u < Hx);

    float wx[9];
    float bxr = 0, bxz = 0, bxn = 0, bhr = 0, bhz = 0, bhn = 0;
    if (act) {
        #pragma unroll
        for (int d = 0; d < 3; ++d) {
            wx[d]     = Wih[(size_t)u * 3 + d];
            wx[3 + d] = Wih[(size_t)(Hx + u) * 3 + d];
            wx[6 + d] = Wih[(size_t)(2 * Hx + u) * 3 + d];
        }
        bxr = bih[u]; bxz = bih[Hx + u]; bxn = bih[2 * Hx + u];
        bhr = bhh[u]; bhz = bhh[Hx + u]; bhn = bhh[2 * Hx + u];
        hls[0][2 * u]     = hinit[(size_t)bb * Hx + u];
        hls[0][2 * u + 1] = hinit[(size_t)(bb + 1) * Hx + u];
    }
    __syncthreads();
    int cur = 0;
    for (int t = 0; t < Tx; ++t) {
        v2f ahr = {bhr, bhr}, ahz = {bhz, bhz}, ahn = {bhn, bhn};
        if (act) {
            const float* hb = hls[cur];
            const v2f* wp = (const v2f*)Wpk + (size_t)u * 3;
            #pragma unroll 2
            for (int j = 0; j < KJ; ++j) {
                v4f h4 = *(const v4f*)(hb + 4 * j);
                v2f wr = wp[0], wz = wp[1], wn = wp[2];
                pk_lo(ahr, wr, h4.xy); pk_hi(ahr, wr, h4.zw);
                pk_lo(ahz, wz, h4.xy); pk_hi(ahz, wz, h4.zw);
                pk_lo(ahn, wn, h4.xy); pk_hi(ahn, wn, h4.zw);
                wp += 3 * Hx;
            }
            v2f x0 = *(const v2f*)(xT + (size_t)t * 192 + 0 * 64 + bb);
            v2f x1 = *(const v2f*)(xT + (size_t)t * 192 + 1 * 64 + bb);
            v2f x2 = *(const v2f*)(xT + (size_t)t * 192 + 2 * 64 + bb);
            v2f axr = {bxr, bxr}, axz = {bxz, bxz}, axn = {bxn, bxn};
            axr += wx[0] * x0 + wx[1] * x1 + wx[2] * x2;
            axz += wx[3] * x0 + wx[4] * x1 + wx[5] * x2;
            axn += wx[6] * x0 + wx[7] * x1 + wx[8] * x2;
            v2f hp; hp.x = hls[cur][2 * u]; hp.y = hls[cur][2 * u + 1];
            v2f r, z, n, hn2;
            r.x = sigf(axr.x + ahr.x); r.y = sigf(axr.y + ahr.y);
            z.x = sigf(axz.x + ahz.x); z.y = sigf(axz.y + ahz.y);
            n.x = tanhf(axn.x + r.x * ahn.x); n.y = tanhf(axn.y + r.y * ahn.y);
            hn2 = (1.0f - z) * n + z * hp;
            hls[cur ^ 1][2 * u]     = hn2.x;
            hls[cur ^ 1][2 * u + 1] = hn2.y;
            *(v2f*)(outL + (size_t)t * 25600 + u * 64 + bb) = hn2;
        }
        __syncthreads();
        cur ^= 1;
    }
}

// Persistent layer-1/2 recurrence over one TT-step chunk. xg precomputed.
__global__ __launch_bounds__(512) void k_rec12(
    const float* __restrict__ xg, const float* __restrict__ hinit,
    const float* __restrict__ Wpk, const float* __restrict__ bhh,
    float* __restrict__ outL, int c) {
    __shared__ __align__(16) float hls[2][2 * Hx];
    const int u = threadIdx.x;
    const int bp = blockIdx.x, bb = bp * 2;
    const bool act = (u < Hx);
    float bhr = 0, bhz = 0, bhn = 0;
    if (act) {
        bhr = bhh[u]; bhz = bhh[Hx + u]; bhn = bhh[2 * Hx + u];
        v2f h0v;
        if (c == 0) {
            h0v.x = hinit[(size_t)bb * Hx + u];
            h0v.y = hinit[(size_t)(bb + 1) * Hx + u];
        } else {
            h0v = *(const v2f*)(outL + (size_t)(c * TT - 1) * 25600 + u * 64 + bb);
        }
        hls[0][2 * u] = h0v.x; hls[0][2 * u + 1] = h0v.y;
    }
    __syncthreads();
    int cur = 0;
    for (int tt = 0; tt < TT; ++tt) {
        int t = c * TT + tt;
        v2f ahr = {bhr, bhr}, ahz = {bhz, bhz}, ahn = {bhn, bhn};
        if (act) {
            const float* hb = hls[cur];
            const v2f* wp = (const v2f*)Wpk + (size_t)u * 3;
            #pragma unroll 2
            for (int j = 0; j < KJ; ++j) {
                v4f h4 = *(const v4f*)(hb + 4 * j);
                v2f wr = wp[0], wz = wp[1], wn = wp[2];
                pk_lo(ahr, wr, h4.xy); pk_hi(ahr, wr, h4.zw);
                pk_lo(ahz, wz, h4.xy); pk_hi(ahz, wz, h4.zw);
                pk_lo(ahn, wn, h4.xy); pk_hi(ahn, wn, h4.zw);
                wp += 3 * Hx;
            }
            const v2f* xp = (const v2f*)xg + (size_t)tt * 38400 + bp * 1200;
            v2f axr = xp[u], axz = xp[Hx + u], axn = xp[2 * Hx + u];
            v2f hp; hp.x = hls[cur][2 * u]; hp.y = hls[cur][2 * u + 1];
            v2f r, z, n, hn2;
            r.x = sigf(axr.x + ahr.x); r.y = sigf(axr.y + ahr.y);
            z.x = sigf(axz.x + ahz.x); z.y = sigf(axz.y + ahz.y);
            n.x = tanhf(axn.x + r.x * ahn.x); n.y = tanhf(axn.y + r.y * ahn.y);
            hn2 = (1.0f - z) * n + z * hp;
            hls[cur ^ 1][2 * u]     = hn2.x;
            hls[cur ^ 1][2 * u + 1] = hn2.y;
            *(v2f*)(outL + (size_t)t * 25600 + u * 64 + bb) = hn2;
        }
        __syncthreads();
        cur ^= 1;
    }
}

// abk = exp(out0 @ W_win^T + b_win), parallel over t. grid 800 x 256.
__global__ __launch_bounds__(256) void k_abk(const float* __restrict__ out0,
    const float* __restrict__ Wwin, const float* __restrict__ bwin,
    float* __restrict__ abk) {
    int t = blockIdx.x;
    int b = threadIdx.x & 63;
    int js = threadIdx.x >> 6;
    int j0 = js * 8;
    int nj = min(8, 30 - j0);
    float acc[8];
    for (int i = 0; i < nj; i++) acc[i] = bwin[j0 + i];
    const float* o = out0 + (size_t)t * 25600;
    for (int k = 0; k < Hx; k++) {
        float hv = o[k * 64 + b];
        for (int i = 0; i < nj; i++) acc[i] += Wwin[(j0 + i) * Hx + k] * hv;
    }
    for (int i = 0; i < nj; i++)
        abk[(size_t)t * 1920 + (j0 + i) * 64 + b] = expf(acc[i]);
}

__global__ void k_cumsum(float* __restrict__ abk) {
    int tid = blockIdx.x * blockDim.x + threadIdx.x;
    if (tid >= Kx * Bx) return;
    int b = tid & 63;
    int k = tid >> 6;
    float run = 0.f;
    size_t base = (size_t)(20 + k) * 64 + b;
    for (int t = 0; t < Tx; t++) {
        size_t i = (size_t)t * 1920 + base;
        run += abk[i];
        abk[i] = run;
    }
}

__global__ __launch_bounds__(256) void k_window(const float* __restrict__ abk,
    const float* __restrict__ ohT, float* __restrict__ win) {
    int t = blockIdx.x;
    int b = threadIdx.x & 63;
    int sub = threadIdx.x >> 6;
    __shared__ float phi[Ux][64];

    float al[Kx], be[Kx], kc[Kx];
    const float* ab = abk + (size_t)t * 1920;
    #pragma unroll
    for (int k = 0; k < Kx; k++) {
        al[k] = ab[k * 64 + b];
        be[k] = ab[(10 + k) * 64 + b];
        kc[k] = ab[(20 + k) * 64 + b];
    }
    for (int u = sub * 20; u < sub * 20 + 20; u++) {
        float s = 0.f;
        float uf = (float)u;
        #pragma unroll
        for (int k = 0; k < Kx; k++) {
            float d = kc[k] - uf;
            s += al[k] * __expf(-be[k] * d * d);
        }
        phi[u][b] = s;
    }
    __syncthreads();

    int v0 = sub * 15;
    int nv = min(15, Vx - v0);
    float acc[15];
    for (int i = 0; i < nv; i++) acc[i] = 0.f;
    for (int u = 0; u < Ux; u++) {
        float pv = phi[u][b];
        const float* oh = ohT + (size_t)(u * Vx) * 64;
        for (int i = 0; i < nv; i++) acc[i] += pv * oh[(v0 + i) * 64 + b];
    }
    for (int i = 0; i < nv; i++)
        win[(size_t)t * 3648 + (v0 + i) * 64 + b] = acc[i];
}

// Input-side projection for layers 1/2, one TT-step chunk.
// grid (TT, 75), block 256: 16 gate rows per block-y tile, 4 per thread.
__global__ __launch_bounds__(256) void k_xg(const float* __restrict__ outprev,
    const float* __restrict__ win, const float* __restrict__ xT,
    const float* __restrict__ Wih, const float* __restrict__ bih,
    float* __restrict__ xg, int c) {
    int tt = blockIdx.x;
    int gt = blockIdx.y;
    int t = c * TT + tt;
    int b = threadIdx.x & 63;
    int du = threadIdx.x >> 6;
    int g = gt * 16 + du * 4;

    float a0 = bih[g], a1 = bih[g + 1], a2 = bih[g + 2], a3 = bih[g + 3];
    const float* w0 = Wih + (size_t)g * 460;
    const float* w1 = w0 + 460;
    const float* w2 = w0 + 920;
    const float* w3 = w0 + 1380;

    const float* op = outprev + (size_t)t * 25600;
    for (int d = 0; d < 400; d += 4) {
        float4 q0 = *(const float4*)(w0 + d);
        float4 q1 = *(const float4*)(w1 + d);
        float4 q2 = *(const float4*)(w2 + d);
        float4 q3 = *(const float4*)(w3 + d);
        float i0 = op[d * 64 + b];
        float i1 = op[(d + 1) * 64 + b];
        float i2 = op[(d + 2) * 64 + b];
        float i3 = op[(d + 3) * 64 + b];
        a0 += q0.x * i0 + q0.y * i1 + q0.z * i2 + q0.w * i3;
        a1 += q1.x * i0 + q1.y * i1 + q1.z * i2 + q1.w * i3;
        a2 += q2.x * i0 + q2.y * i1 + q2.z * i2 + q2.w * i3;
        a3 += q3.x * i0 + q3.y * i1 + q3.z * i2 + q3.w * i3;
    }
    const float* wp = win + (size_t)t * 3648;
    for (int d = 0; d < Vx; d++) {
        float iv = wp[d * 64 + b];
        a0 += w0[400 + d] * iv;
        a1 += w1[400 + d] * iv;
        a2 += w2[400 + d] * iv;
        a3 += w3[400 + d] * iv;
    }
    const float* xp = xT + (size_t)t * 192;
    #pragma unroll
    for (int d = 0; d < 3; d++) {
        float iv = xp[d * 64 + b];
        a0 += w0[457 + d] * iv;
        a1 += w1[457 + d] * iv;
        a2 += w2[457 + d] * iv;
        a3 += w3[457 + d] * iv;
    }
    size_t o = (size_t)tt * 76800 + (size_t)(b >> 1) * 2400 + (size_t)g * 2 + (b & 1);
    xg[o] = a0;
    xg[o + 2] = a1;
    xg[o + 4] = a2;
    xg[o + 6] = a3;
}

// MDN head: out[(b*T+t)*121 + j], tanh on j in [100,120). grid 800 x 256.
__global__ __launch_bounds__(256) void k_mdn(const float* __restrict__ out2,
    const float* __restrict__ Wm, const float* __restrict__ bm,
    float* __restrict__ out) {
    int t = blockIdx.x;
    int b = threadIdx.x & 63;
    int js = threadIdx.x >> 6;
    int j0 = js * 31;
    int nj = min(31, 121 - j0);
    float acc[31];
    for (int i = 0; i < nj; i++) acc[i] = bm[j0 + i];
    const float* o = out2 + (size_t)t * 25600;
    for (int k = 0; k < Hx; k += 4) {
        float i0 = o[k * 64 + b];
        float i1 = o[(k + 1) * 64 + b];
        float i2 = o[(k + 2) * 64 + b];
        float i3 = o[(k + 3) * 64 + b];
        for (int i = 0; i < nj; i++) {
            const float* w = Wm + (size_t)(j0 + i) * Hx + k;
            float4 q = *(const float4*)w;
            acc[i] += q.x * i0 + q.y * i1 + q.z * i2 + q.w * i3;
        }
    }
    size_t rb = ((size_t)b * Tx + t) * 121;
    for (int i = 0; i < nj; i++) {
        int j = j0 + i;
        float v = acc[i];
        if (j >= 100 && j < 120) v = tanhf(v);
        out[rb + j] = v;
    }
}

extern "C" void kernel_launch(void* const* d_in, const int* in_sizes, int n_in,
                              void* d_out, int out_size, void* d_ws, size_t ws_size,
                              hipStream_t stream) {
    const float* x    = (const float*)d_in[0];
    const float* oneh = (const float*)d_in[1];
    const float* h0i  = (const float*)d_in[2];
    const float* h1i  = (const float*)d_in[3];
    const float* h2i  = (const float*)d_in[4];
    const float* Wih0 = (const float*)d_in[5];
    const float* Whh0 = (const float*)d_in[6];
    const float* bih0 = (const float*)d_in[7];
    const float* bhh0 = (const float*)d_in[8];
    const float* Wih1 = (const float*)d_in[9];
    const float* Whh1 = (const float*)d_in[10];
    const float* bih1 = (const float*)d_in[11];
    const float* bhh1 = (const float*)d_in[12];
    const float* Wwin = (const float*)d_in[13];
    const float* bwin = (const float*)d_in[14];
    const float* Wmdn = (const float*)d_in[15];
    const float* bmdn = (const float*)d_in[16];

    float* ws    = (float*)d_ws;
    float* out0  = ws;                  // 20,480,000
    float* out12 = ws + 20480000;       // 20,480,000
    float* winb  = ws + 40960000;       //  2,918,400
    float* abk   = ws + 43878400;       //  1,536,000
    float* xg    = ws + 45414400;       //  3,072,000 (TT=40 chunk)
    float* xT    = ws + 48486400;       //    153,600
    float* ohT   = ws + 48640000;       //    291,840
    float* WpkA  = ws + 48931840;       //    480,000
    float* WpkB  = ws + 49411840;       //    480,000
    // total 49,891,840 floats = 199.6 MB

    hipLaunchKernelGGL(k_transpose_x, dim3((Tx * INx * Bx + 255) / 256), dim3(256), 0, stream, x, xT);
    hipLaunchKernelGGL(k_transpose_oh, dim3((Ux * Vx * Bx + 255) / 256), dim3(256), 0, stream, oneh, ohT);
    hipLaunchKernelGGL(k_pack, dim3((3 * KJ * Hx + 255) / 256), dim3(256), 0, stream, Whh0, WpkA);
    hipLaunchKernelGGL(k_pack, dim3((3 * KJ * Hx + 255) / 256), dim3(256), 0, stream, Whh1, WpkB);

    hipLaunchKernelGGL(k_rec0, dim3(32), dim3(512), 0, stream,
                       xT, h0i, Wih0, WpkA, bih0, bhh0, out0);

    hipLaunchKernelGGL(k_abk, dim3(Tx), dim3(256), 0, stream, out0, Wwin, bwin, abk);
    hipLaunchKernelGGL(k_cumsum, dim3(10), dim3(64), 0, stream, abk);
    hipLaunchKernelGGL(k_window, dim3(Tx), dim3(256), 0, stream, abk, ohT, winb);

    // Layer 1 (input: out0, win, x)
    for (int c = 0; c < NC; c++) {
        hipLaunchKernelGGL(k_xg, dim3(TT, 75), dim3(256), 0, stream,
                           out0, winb, xT, Wih1, bih1, xg, c);
        hipLaunchKernelGGL(k_rec12, dim3(32), dim3(512), 0, stream,
                           xg, h1i, WpkB, bhh1, out12, c);
    }
    // Layer 2 (input: out12, win, x), same weights; output reuses out0 buffer
    for (int c = 0; c < NC; c++) {
        hipLaunchKernelGGL(k_xg, dim3(TT, 75), dim3(256), 0, stream,
                           out12, winb, xT, Wih1, bih1, xg, c);
        hipLaunchKernelGGL(k_rec12, dim3(32), dim3(512), 0, stream,
                           xg, h2i, WpkB, bhh1, out0, c);
    }
    hipLaunchKernelGGL(k_mdn, dim3(Tx), dim3(256), 0, stream, out0, Wmdn, bmdn, (float*)d_out);
}